// Round 11
// baseline (30.166 us; speedup 1.0000x reference)
//
#include <hip/hip_runtime.h>

// LocallyConnected2d: out[b,o,ho,wo] = bias[o,ho,wo]
//   + sum_{c,ki,kj} x[b,c,ho+ki,wo+kj] * w[o,c,ho,wo,ki*3+kj]
//
// Round-11: o-blocking (x reuse). r5==r7==r8==r10==26.4us across four
// sync/staging schemes -> the invariant x data path is the limit
// (~293MB of x L1 requests GPU-wide; each x row re-read by all 32 o).
// Block now covers OG=4 o values: x registers loaded once per body,
// FMA'd against 4 weight rows -> x L1/TA traffic /4, FLOP:byte x4.
//  - grid = 8 og x 62 ho = 496 blocks, 256 threads (4 waves = c-groups).
//  - per wave LDS: 2 buf x 4 o-rows x 576 floats = 18KB (x4 waves = 73.7KB).
//  - staging: 4 rows per body, w16 DMA + w4 tail (r10 STAGE), double-
//    buffered; counted vmcnt: [stage(cc):12][x:12][stage(cc+1):12] ->
//    vmcnt(24); body3 vmcnt(12). sched_barrier(0) pins groups (r6 lesson:
//    no asm memory clobbers).
//  - lane (q,l): q=lane>>4 owns b=2q,2q+1; l=lane&15 owns wo=4l..4l+3
//    (f4+f2 x window, no cross-lane; l=15 dummy f2 flows only into
//    discarded wo 62/63 — verified r5-r10 edge behavior).
//  - ds_read: 9x b128 per o-row; quadrants broadcast (same addr, free),
//    within-quadrant 2-way alias free (m136).
//  - epilogue: stash [oo][b][64] per wave (2048 floats, fits in buf area),
//    ONE __syncthreads, cross-wave reduce, bias, coalesced store.

#define BB 8
#define CC 16
#define HH 64
#define WW 64
#define OO 32
#define HO 62
#define WO 62
#define OG 4              // o per block
#define NLOC (HO * WO)    // 3844
#define TOTAL (OO * NLOC) // 123008

typedef float f4 __attribute__((ext_vector_type(4)));
typedef float f2 __attribute__((ext_vector_type(2)));

__device__ __forceinline__ void async_f32_to_lds(const float* g, float* l) {
  __builtin_amdgcn_global_load_lds((const __attribute__((address_space(1))) void*)g,
                                   (__attribute__((address_space(3))) void*)l,
                                   4, 0, 0);
}
__device__ __forceinline__ void async_f32x4_to_lds(const float* g, float* l) {
  __builtin_amdgcn_global_load_lds((const __attribute__((address_space(1))) void*)g,
                                   (__attribute__((address_space(3))) void*)l,
                                   16, 0, 0);
}

__global__ __launch_bounds__(256) void lc2d_kernel(
    const float* __restrict__ x, const float* __restrict__ weight,
    const float* __restrict__ bias, float* __restrict__ out) {
  // [wave][buf(2)][oo(4)][576]
  __shared__ __align__(16) float smem[4 * 2 * OG * 576];

  const int tid  = threadIdx.x;
  const int lane = tid & 63;
  const int wave = tid >> 6;
  const int l = lane & 15;   // wo-group: wo = 4l..4l+3
  const int q = lane >> 4;   // b-group:  b  = 2q, 2q+1
  const int ho = blockIdx.x % HO;
  const int og = blockIdx.x / HO;

  float* wbuf = smem + wave * (2 * OG * 576);

  const int colbase = 4 * l;
  const int f2off = (l < 15) ? 4 : -4;  // l=15: dummy in-bounds read, discarded

  // weight row base for (o = og*OG + oo, c = wave*4 + cc, ho):
  const float* wbase = weight + ((size_t)(og * OG) * CC + wave * 4) * (NLOC * 9)
                              + (size_t)ho * (WO * 9);

  // stage one 558-float weight row: 2x w16 DMA + 1x w4 tail
#define STAGE_ROW(SRC, DST)                                            \
  {                                                                    \
    async_f32x4_to_lds((SRC) + lane * 4, (DST));                       \
    async_f32x4_to_lds((SRC) + 256 + lane * 4, (DST) + 256);           \
    if (lane < 46) async_f32_to_lds((SRC) + 512 + lane, (DST) + 512);  \
  }
  // stage all OG rows of one c into DST buffer (12 VMEM)
#define STAGE_BODY(cc, DST)                                            \
  {                                                                    \
    _Pragma("unroll")                                                  \
    for (int oo = 0; oo < OG; ++oo)                                    \
      STAGE_ROW(wbase + ((size_t)oo * CC + (cc)) * (NLOC * 9),         \
                (DST) + oo * 576);                                     \
  }

  // ---- prologue: stage cc=0 (12 VMEM) ----
  STAGE_BODY(0, wbuf)

  f4 acc[2][OG];
#pragma unroll
  for (int bo = 0; bo < 2; ++bo)
#pragma unroll
    for (int oo = 0; oo < OG; ++oo) acc[bo][oo] = (f4)0.f;

#pragma unroll
  for (int cc = 0; cc < 4; ++cc) {
    const float* cur = wbuf + (cc & 1) * (OG * 576);
    float* nxt = wbuf + ((cc + 1) & 1) * (OG * 576);
    const int c = wave * 4 + cc;

    __builtin_amdgcn_sched_barrier(0);
    // ---- group 1: ALL x loads for this body (12 VMEM) ----
    f4 v4[2][3];
    f2 v2[2][3];
#pragma unroll
    for (int bo = 0; bo < 2; ++bo) {
      const float* xb = x + ((size_t)(2 * q + bo) * CC + c) * (HH * WW)
                          + (size_t)ho * WW + colbase;
#pragma unroll
      for (int r = 0; r < 3; ++r) {
        v4[bo][r] = *(const f4*)(xb + r * WW);
        v2[bo][r] = *(const f2*)(xb + r * WW + f2off);
      }
    }
    __builtin_amdgcn_sched_barrier(0);
    // ---- group 2: issue stage(cc+1) (12 VMEM) ----
    if (cc < 3) STAGE_BODY(cc + 1, nxt)
    __builtin_amdgcn_sched_barrier(0);
    // ---- group 3: drain stage(cc); x + stage(cc+1) stay in flight ----
    if (cc < 3) {
      asm volatile("s_waitcnt vmcnt(24)");
    } else {
      asm volatile("s_waitcnt vmcnt(12)");
    }
    __builtin_amdgcn_sched_barrier(0);

    // ---- group 4: per-o weights from LDS + FMAs (x regs reused 4x) ----
#pragma unroll
    for (int oo = 0; oo < OG; ++oo) {
      f4 wq[9];
#pragma unroll
      for (int k = 0; k < 9; ++k)
        wq[k] = *(const f4*)(cur + oo * 576 + 36 * l + 4 * k);

#pragma unroll
      for (int bo = 0; bo < 2; ++bo) {
#pragma unroll
        for (int w4 = 0; w4 < 4; ++w4) {
          float s = 0.f;
#pragma unroll
          for (int r = 0; r < 3; ++r) {
#pragma unroll
            for (int j = 0; j < 3; ++j) {
              const int e = w4 + j;                 // 0..5, compile-time
              const int wi = w4 * 9 + r * 3 + j;    // 0..35, compile-time
              const float xv = (e < 4) ? v4[bo][r][e] : v2[bo][r][e - 4];
              s += xv * wq[wi >> 2][wi & 3];
            }
          }
          acc[bo][oo][w4] += s;
        }
      }
    }
  }
#undef STAGE_BODY
#undef STAGE_ROW

  // ---- stash partials: [oo][b][64] in this wave's region (2048 floats;
  // DMA all drained at body3's vmcnt(12); ordered after wq reads by data dep)
#pragma unroll
  for (int oo = 0; oo < OG; ++oo)
#pragma unroll
    for (int bo = 0; bo < 2; ++bo)
      *(f4*)(wbuf + (oo * 8 + 2 * q + bo) * 64 + colbase) = acc[bo][oo];
  __syncthreads();  // the only block-wide barrier

  // ---- reduce 4 wave-partials, add bias, coalesced store ----
  for (int p = tid; p < OG * 8 * 64; p += 256) {
    const int oo = p >> 9;
    const int b  = (p >> 6) & 7;
    const int wo = p & 63;
    if (wo < WO) {
      float s = smem[0 * 4608 + p] + smem[1 * 4608 + p]
              + smem[2 * 4608 + p] + smem[3 * 4608 + p];
      const int loc = (og * OG + oo) * NLOC + ho * WO + wo;
      out[(size_t)b * TOTAL + loc] = s + bias[loc];
    }
  }
}

extern "C" void kernel_launch(void* const* d_in, const int* in_sizes, int n_in,
                              void* d_out, int out_size, void* d_ws, size_t ws_size,
                              hipStream_t stream) {
  const float* x = (const float*)d_in[0];
  const float* w = (const float*)d_in[1];
  const float* bias = (const float*)d_in[2];
  float* out = (float*)d_out;

  hipLaunchKernelGGL(lc2d_kernel, dim3((OO / OG) * HO), dim3(256), 0, stream,
                     x, w, bias, out);
}

// Round 12
// 30.112 us; speedup vs baseline: 1.0018x; 1.0018x over previous
//
#include <hip/hip_runtime.h>

// LocallyConnected2d: out[b,o,ho,wo] = bias[o,ho,wo]
//   + sum_{c,ki,kj} x[b,c,ho+ki,wo+kj] * w[o,c,ho,wo,ki*3+kj]
//
// Round-12 = Round-11 with OG 4->2: same x-reuse idea, occupancy restored.
//   r11 (OG4): VMEM/CU -60% but LDS 73.7KB -> 2 blocks/CU = 8 waves -> 30us
//   (latency-bound: TLP collapse ate the throughput win).
//   r10 (OG1): 31 waves but VMEM 1860/CU -> 26.4us (issue-bound).
//   OG2: LDS 36.9KB -> 4 blocks/CU cap, grid 992 -> ~15.5 waves/CU AND
//   VMEM ~1116/CU (x instrs & x L1 bytes halved vs r10; weight traffic
//   compulsory/unchanged; DS work conserved).
//  - grid = 16 og x 62 ho = 992 blocks, 256 threads (4 waves = c-groups).
//  - per wave LDS: 2 buf x 2 o-rows x 576 floats = 9.2KB (x4 waves = 36.9KB).
//  - staging: w16 DMA + w4 tail per 558-float row, double-buffered; counted
//    vmcnt per body: [stage(cc):6][x:12][stage(cc+1):6] -> vmcnt(18) drains
//    exactly stage(cc); body3 vmcnt(12). sched_barrier(0) pins groups; no
//    asm memory clobbers (r6 spill lesson). Same scheme that passed r11.
//  - lane (q,l): q=lane>>4 owns b=2q,2q+1; l=lane&15 owns wo=4l..4l+3
//    (f4+f2 window; l=15 dummy f2 flows only into discarded wo 62/63).
//  - epilogue: stash [oo][b][64] per wave, ONE __syncthreads, cross-wave
//    reduce, bias, coalesced store.

#define BB 8
#define CC 16
#define HH 64
#define WW 64
#define OO 32
#define HO 62
#define WO 62
#define OG 2                    // o per block
#define WSTRIDE (2 * OG * 576)  // floats per wave region (1152*OG)
#define NLOC (HO * WO)          // 3844
#define TOTAL (OO * NLOC)       // 123008

typedef float f4 __attribute__((ext_vector_type(4)));
typedef float f2 __attribute__((ext_vector_type(2)));

__device__ __forceinline__ void async_f32_to_lds(const float* g, float* l) {
  __builtin_amdgcn_global_load_lds((const __attribute__((address_space(1))) void*)g,
                                   (__attribute__((address_space(3))) void*)l,
                                   4, 0, 0);
}
__device__ __forceinline__ void async_f32x4_to_lds(const float* g, float* l) {
  __builtin_amdgcn_global_load_lds((const __attribute__((address_space(1))) void*)g,
                                   (__attribute__((address_space(3))) void*)l,
                                   16, 0, 0);
}

__global__ __launch_bounds__(256) void lc2d_kernel(
    const float* __restrict__ x, const float* __restrict__ weight,
    const float* __restrict__ bias, float* __restrict__ out) {
  // [wave][buf(2)][oo(OG)][576]
  __shared__ __align__(16) float smem[4 * WSTRIDE];

  const int tid  = threadIdx.x;
  const int lane = tid & 63;
  const int wave = tid >> 6;
  const int l = lane & 15;   // wo-group: wo = 4l..4l+3
  const int q = lane >> 4;   // b-group:  b  = 2q, 2q+1
  const int ho = blockIdx.x % HO;
  const int og = blockIdx.x / HO;

  float* wbuf = smem + wave * WSTRIDE;

  const int colbase = 4 * l;
  const int f2off = (l < 15) ? 4 : -4;  // l=15: dummy in-bounds read, discarded

  // weight row base for (o = og*OG + oo, c = wave*4 + cc, ho):
  const float* wbase = weight + ((size_t)(og * OG) * CC + wave * 4) * (NLOC * 9)
                              + (size_t)ho * (WO * 9);

  // stage one 558-float weight row: 2x w16 DMA + 1x w4 tail
#define STAGE_ROW(SRC, DST)                                            \
  {                                                                    \
    async_f32x4_to_lds((SRC) + lane * 4, (DST));                       \
    async_f32x4_to_lds((SRC) + 256 + lane * 4, (DST) + 256);           \
    if (lane < 46) async_f32_to_lds((SRC) + 512 + lane, (DST) + 512);  \
  }
  // stage all OG rows of one c into DST buffer (6 VMEM)
#define STAGE_BODY(cc, DST)                                            \
  {                                                                    \
    _Pragma("unroll")                                                  \
    for (int oo = 0; oo < OG; ++oo)                                    \
      STAGE_ROW(wbase + ((size_t)oo * CC + (cc)) * (NLOC * 9),         \
                (DST) + oo * 576);                                     \
  }

  // ---- prologue: stage cc=0 (6 VMEM) ----
  STAGE_BODY(0, wbuf)

  f4 acc[2][OG];
#pragma unroll
  for (int bo = 0; bo < 2; ++bo)
#pragma unroll
    for (int oo = 0; oo < OG; ++oo) acc[bo][oo] = (f4)0.f;

#pragma unroll
  for (int cc = 0; cc < 4; ++cc) {
    const float* cur = wbuf + (cc & 1) * (OG * 576);
    float* nxt = wbuf + ((cc + 1) & 1) * (OG * 576);
    const int c = wave * 4 + cc;

    __builtin_amdgcn_sched_barrier(0);
    // ---- group 1: ALL x loads for this body (12 VMEM) ----
    f4 v4[2][3];
    f2 v2[2][3];
#pragma unroll
    for (int bo = 0; bo < 2; ++bo) {
      const float* xb = x + ((size_t)(2 * q + bo) * CC + c) * (HH * WW)
                          + (size_t)ho * WW + colbase;
#pragma unroll
      for (int r = 0; r < 3; ++r) {
        v4[bo][r] = *(const f4*)(xb + r * WW);
        v2[bo][r] = *(const f2*)(xb + r * WW + f2off);
      }
    }
    __builtin_amdgcn_sched_barrier(0);
    // ---- group 2: issue stage(cc+1) (6 VMEM) ----
    if (cc < 3) STAGE_BODY(cc + 1, nxt)
    __builtin_amdgcn_sched_barrier(0);
    // ---- group 3: drain stage(cc); x + stage(cc+1) stay in flight ----
    if (cc < 3) {
      asm volatile("s_waitcnt vmcnt(18)");
    } else {
      asm volatile("s_waitcnt vmcnt(12)");
    }
    __builtin_amdgcn_sched_barrier(0);

    // ---- group 4: per-o weights from LDS + FMAs (x regs reused OG x) ----
#pragma unroll
    for (int oo = 0; oo < OG; ++oo) {
      f4 wq[9];
#pragma unroll
      for (int k = 0; k < 9; ++k)
        wq[k] = *(const f4*)(cur + oo * 576 + 36 * l + 4 * k);

#pragma unroll
      for (int bo = 0; bo < 2; ++bo) {
#pragma unroll
        for (int w4 = 0; w4 < 4; ++w4) {
          float s = 0.f;
#pragma unroll
          for (int r = 0; r < 3; ++r) {
#pragma unroll
            for (int j = 0; j < 3; ++j) {
              const int e = w4 + j;                 // 0..5, compile-time
              const int wi = w4 * 9 + r * 3 + j;    // 0..35, compile-time
              const float xv = (e < 4) ? v4[bo][r][e] : v2[bo][r][e - 4];
              s += xv * wq[wi >> 2][wi & 3];
            }
          }
          acc[bo][oo][w4] += s;
        }
      }
    }
  }
#undef STAGE_BODY
#undef STAGE_ROW

  // ---- stash partials: [oo][b][64] in this wave's region (1024 floats;
  // DMA drained at body3's vmcnt(12); ordered after wq reads by data dep)
#pragma unroll
  for (int oo = 0; oo < OG; ++oo)
#pragma unroll
    for (int bo = 0; bo < 2; ++bo)
      *(f4*)(wbuf + (oo * 8 + 2 * q + bo) * 64 + colbase) = acc[bo][oo];
  __syncthreads();  // the only block-wide barrier

  // ---- reduce 4 wave-partials, add bias, coalesced store ----
  for (int p = tid; p < OG * 8 * 64; p += 256) {
    const int oo = p >> 9;
    const int b  = (p >> 6) & 7;
    const int wo = p & 63;
    if (wo < WO) {
      float s = smem[0 * WSTRIDE + p] + smem[1 * WSTRIDE + p]
              + smem[2 * WSTRIDE + p] + smem[3 * WSTRIDE + p];
      const int loc = (og * OG + oo) * NLOC + ho * WO + wo;
      out[(size_t)b * TOTAL + loc] = s + bias[loc];
    }
  }
}

extern "C" void kernel_launch(void* const* d_in, const int* in_sizes, int n_in,
                              void* d_out, int out_size, void* d_ws, size_t ws_size,
                              hipStream_t stream) {
  const float* x = (const float*)d_in[0];
  const float* w = (const float*)d_in[1];
  const float* bias = (const float*)d_in[2];
  float* out = (float*)d_out;

  hipLaunchKernelGGL(lc2d_kernel, dim3((OO / OG) * HO), dim3(256), 0, stream,
                     x, w, bias, out);
}

// Round 13
// 29.752 us; speedup vs baseline: 1.0139x; 1.0121x over previous
//
#include <hip/hip_runtime.h>

// LocallyConnected2d: out[b,o,ho,wo] = bias[o,ho,wo]
//   + sum_{c,ki,kj} x[b,c,ho+ki,wo+kj] * w[o,c,ho,wo,ki*3+kj]
//
// Round-13: producer-wave full prefetch (decoupled vmcnt queues).
//   Proven constraint from r5-r12: with per-wave in-order vmcnt, stage lead
//   <= x-prefetch depth + 1 body; all variants had ~1-body lead -> exposed
//   weight latency every body. Fix: vmcnt is PER-WAVE, so wave 0 stages ALL
//   16 weight rows upfront (its own queue), while every wave pre-issues its
//   body-0 x loads (queues contain only x). The single __syncthreads drains
//   all queues IN PARALLEL -> weight + x latency paid once, overlapped.
//   After the barrier: zero stage waits, no dbuf, no inline asm.
//  - block = 512 thr (8 waves) for one (o,ho); wave w owns c = {2w, 2w+1}.
//  - LDS: 16 rows x 576 floats = 36.9KB, staged once (no double buffer).
//  - lane (q,l): q=lane>>4 owns b=2q,2q+1; l=lane&15 owns wo=4l..4l+3
//    (f4+f2 window; l=15 dummy f2 flows only into discarded wo 62/63).
//  - body t=0: x already in regs; t=1: x at-use (hidden under ds_read+TLP).
//  - epilogue: wave w stashes into its own row-2w region (wave-local, no
//    race), ONE barrier, 8-way reduce, bias, coalesced store.

#define BB 8
#define CC 16
#define HH 64
#define WW 64
#define OO 32
#define HO 62
#define WO 62
#define NLOC (HO * WO)    // 3844
#define TOTAL (OO * NLOC) // 123008

typedef float f4 __attribute__((ext_vector_type(4)));
typedef float f2 __attribute__((ext_vector_type(2)));

__device__ __forceinline__ void async_f32_to_lds(const float* g, float* l) {
  __builtin_amdgcn_global_load_lds((const __attribute__((address_space(1))) void*)g,
                                   (__attribute__((address_space(3))) void*)l,
                                   4, 0, 0);
}
__device__ __forceinline__ void async_f32x4_to_lds(const float* g, float* l) {
  __builtin_amdgcn_global_load_lds((const __attribute__((address_space(1))) void*)g,
                                   (__attribute__((address_space(3))) void*)l,
                                   16, 0, 0);
}

__global__ __launch_bounds__(512) void lc2d_kernel(
    const float* __restrict__ x, const float* __restrict__ weight,
    const float* __restrict__ bias, float* __restrict__ out) {
  __shared__ __align__(16) float smem[CC * 576];  // 36.9 KB

  const int tid  = threadIdx.x;
  const int lane = tid & 63;
  const int wave = tid >> 6;          // 0..7
  const int l = lane & 15;            // wo-group: wo = 4l..4l+3
  const int q = lane >> 4;            // b-group:  b  = 2q, 2q+1
  const int ho = blockIdx.x % HO;
  const int o  = blockIdx.x / HO;

  const int colbase = 4 * l;
  const int f2off = (l < 15) ? 4 : -4;  // l=15: dummy in-bounds read, discarded

  // ---- producer: wave 0 stages ALL 16 weight rows (48 DMA, own queue) ----
  if (wave == 0) {
    const float* wb = weight + ((size_t)o * CC * NLOC + (size_t)ho * WO) * 9;
#pragma unroll
    for (int c = 0; c < CC; ++c) {
      const float* src = wb + (size_t)c * (NLOC * 9);
      float* dst = smem + c * 576;
      async_f32x4_to_lds(src + lane * 4, dst);
      async_f32x4_to_lds(src + 256 + lane * 4, dst + 256);
      if (lane < 46) async_f32_to_lds(src + 512 + lane, dst + 512);
    }
  }

  // ---- all waves: pre-issue body-0 x loads (own queue: x only) ----
  const int c0 = 2 * wave;
  f4 v4[2][3];
  f2 v2[2][3];
#pragma unroll
  for (int bo = 0; bo < 2; ++bo) {
    const float* xb = x + ((size_t)(2 * q + bo) * CC + c0) * (HH * WW)
                        + (size_t)ho * WW + colbase;
#pragma unroll
    for (int r = 0; r < 3; ++r) {
      v4[bo][r] = *(const f4*)(xb + r * WW);
      v2[bo][r] = *(const f2*)(xb + r * WW + f2off);
    }
  }

  __syncthreads();  // drains ALL queues in parallel: weights in LDS, x in regs

  f4 acc[2];
  acc[0] = (f4)0.f;
  acc[1] = (f4)0.f;

#pragma unroll
  for (int t = 0; t < 2; ++t) {
    const int c = c0 + t;

    if (t == 1) {
      // body-1 x at-use (regs freed by body-0 FMAs; hidden by ds_read + TLP)
#pragma unroll
      for (int bo = 0; bo < 2; ++bo) {
        const float* xb = x + ((size_t)(2 * q + bo) * CC + c) * (HH * WW)
                            + (size_t)ho * WW + colbase;
#pragma unroll
        for (int r = 0; r < 3; ++r) {
          v4[bo][r] = *(const f4*)(xb + r * WW);
          v2[bo][r] = *(const f2*)(xb + r * WW + f2off);
        }
      }
    }

    // ---- 36 weights (wo=4l..4l+3 x k=0..8): 9x ds_read_b128 ----
    const float* cur = smem + c * 576;
    f4 wq[9];
#pragma unroll
    for (int k = 0; k < 9; ++k)
      wq[k] = *(const f4*)(cur + 36 * l + 4 * k);

#pragma unroll
    for (int bo = 0; bo < 2; ++bo) {
#pragma unroll
      for (int w4 = 0; w4 < 4; ++w4) {
        float s = 0.f;
#pragma unroll
        for (int r = 0; r < 3; ++r) {
#pragma unroll
          for (int j = 0; j < 3; ++j) {
            const int e = w4 + j;                 // 0..5, compile-time
            const int wi = w4 * 9 + r * 3 + j;    // 0..35, compile-time
            const float xv = (e < 4) ? v4[bo][r][e] : v2[bo][r][e - 4];
            s += xv * wq[wi >> 2][wi & 3];
          }
        }
        acc[bo][w4] += s;
      }
    }
  }

  // ---- stash partials into THIS wave's own row-2w region (wave-local:
  // rows 2w/2w+1 are read only by wave w, ordered by wq data dependence) ----
#pragma unroll
  for (int bo = 0; bo < 2; ++bo)
    *(f4*)(smem + c0 * 576 + (2 * q + bo) * 64 + colbase) = acc[bo];
  __syncthreads();

  // ---- reduce 8 wave-partials, add bias, coalesced store (512 thr) ----
  {
    const int b  = tid >> 6;
    const int wo = tid & 63;
    if (wo < WO) {
      float s = 0.f;
#pragma unroll
      for (int w = 0; w < 8; ++w)
        s += smem[(2 * w) * 576 + b * 64 + wo];
      const int loc = o * NLOC + ho * WO + wo;
      out[(size_t)b * TOTAL + loc] = s + bias[loc];
    }
  }
}

extern "C" void kernel_launch(void* const* d_in, const int* in_sizes, int n_in,
                              void* d_out, int out_size, void* d_ws, size_t ws_size,
                              hipStream_t stream) {
  const float* x = (const float*)d_in[0];
  const float* w = (const float*)d_in[1];
  const float* bias = (const float*)d_in[2];
  float* out = (float*)d_out;

  hipLaunchKernelGGL(lc2d_kernel, dim3(OO * HO), dim3(512), 0, stream,
                     x, w, bias, out);
}

// Round 14
// 26.675 us; speedup vs baseline: 1.1309x; 1.1154x over previous
//
#include <hip/hip_runtime.h>

// LocallyConnected2d: out[b,o,ho,wo] = bias[o,ho,wo]
//   + sum_{c,ki,kj} x[b,c,ho+ki,wo+kj] * w[o,c,ho,wo,ki*3+kj]
//
// Round-14 = Round-10 with the weight staging swapped from global_load_lds
// DMA to REGISTER staging (global->VGPR coalesced -> ds_write_b128).
//   Bandwidth model fitting r1-r13: time = effective fabric bytes / ~2.8TB/s
//   (r5/7/8/10: 73MB->26us; r9 1.3x overfetch->34; r1 1.7x->47; r6 +126MB
//   spills->60 at 2.71TB/s measured). But harness fills sustain 6.9TB/s
//   WRITE-only -> reads' 2.8 may not be a fabric wall. Common element of
//   every 26us variant: global_load_lds DMA on the weight stream. This round
//   isolates it: same bytes, same 1KB/instr coalesced pattern, no DMA.
//   17-21us => DMA was the cap; ~26 => fabric read ceiling -> roofline.
//  - NO inline asm, NO sched_barriers: wave-local dbuf ordering is handled
//    by compiler lgkmcnt (same-wave DS is in-order; RAW/WAR per-wave safe).
//  - lane (q,l): q=lane>>4 owns b=2q,2q+1; l=lane&15 owns wo=4l..4l+3
//    (f4+f2 window; l=15 dummy f2 flows only into discarded wo 62/63).
//  - epilogue: stash [b][64] per wave, ONE __syncthreads, 4-wave reduce,
//    bias add, coalesced store (unchanged from r10).

#define BB 8
#define CC 16
#define HH 64
#define WW 64
#define OO 32
#define HO 62
#define WO 62
#define NLOC (HO * WO)    // 3844
#define TOTAL (OO * NLOC) // 123008

typedef float f4 __attribute__((ext_vector_type(4)));
typedef float f2 __attribute__((ext_vector_type(2)));

__global__ __launch_bounds__(256) void lc2d_kernel(
    const float* __restrict__ x, const float* __restrict__ weight,
    const float* __restrict__ bias, float* __restrict__ out) {
  // per wave: two 576-float weight buffers; buf0 reused for partial stash
  __shared__ __align__(16) float smem[4 * 2 * 576];

  const int tid  = threadIdx.x;
  const int lane = tid & 63;
  const int wave = tid >> 6;
  const int l = lane & 15;   // wo-group: wo = 4l..4l+3
  const int q = lane >> 4;   // b-group:  b  = 2q, 2q+1
  const int ho = blockIdx.x % HO;
  const int o  = blockIdx.x / HO;

  float* buf0 = smem + wave * 1152;

  const int colbase = 4 * l;
  const int f2off = (l < 15) ? 4 : -4;  // l=15: dummy in-bounds read, discarded

  const float* wbase = weight + (size_t)(o * CC + wave * 4) * (NLOC * 9)
                              + (size_t)ho * (WO * 9);

  // ---- register-staged row load: 2x coalesced f4 + tail f1 ----
#define WLOAD(SRC, V0, V1, VT)                       \
  {                                                  \
    (V0) = *(const f4*)((SRC) + lane * 4);           \
    (V1) = *(const f4*)((SRC) + 256 + lane * 4);     \
    (VT) = (lane < 46) ? (SRC)[512 + lane] : 0.f;    \
  }
#define WSTORE(DST, V0, V1, VT)                      \
  {                                                  \
    *(f4*)((DST) + lane * 4) = (V0);                 \
    *(f4*)((DST) + 256 + lane * 4) = (V1);           \
    if (lane < 46) (DST)[512 + lane] = (VT);         \
  }

  // ---- prologue: stage cc=0 into buf0 through registers ----
  {
    f4 a0, a1; float at;
    WLOAD(wbase, a0, a1, at)
    WSTORE(buf0, a0, a1, at)
  }

  f4 acc[2];
  acc[0] = (f4)0.f;
  acc[1] = (f4)0.f;

#pragma unroll
  for (int cc = 0; cc < 4; ++cc) {
    const float* cur = buf0 + (cc & 1) * 576;
    float* nxt = buf0 + ((cc + 1) & 1) * 576;
    const int c = wave * 4 + cc;

    // issue next row's global loads early (compiler schedules/waits)
    f4 n0, n1; float nt;
    if (cc < 3) WLOAD(wbase + (size_t)(cc + 1) * (NLOC * 9), n0, n1, nt)

    // x loads for this body
    f4 v4[2][3];
    f2 v2[2][3];
#pragma unroll
    for (int bo = 0; bo < 2; ++bo) {
      const float* xb = x + ((size_t)(2 * q + bo) * CC + c) * (HH * WW)
                          + (size_t)ho * WW + colbase;
#pragma unroll
      for (int r = 0; r < 3; ++r) {
        v4[bo][r] = *(const f4*)(xb + r * WW);
        v2[bo][r] = *(const f2*)(xb + r * WW + f2off);
      }
    }

    // weights from LDS (9x ds_read_b128) + FMAs
    f4 wq[9];
#pragma unroll
    for (int k = 0; k < 9; ++k)
      wq[k] = *(const f4*)(cur + 36 * l + 4 * k);

#pragma unroll
    for (int bo = 0; bo < 2; ++bo) {
#pragma unroll
      for (int w4 = 0; w4 < 4; ++w4) {
        float s = 0.f;
#pragma unroll
        for (int r = 0; r < 3; ++r) {
#pragma unroll
          for (int j = 0; j < 3; ++j) {
            const int e = w4 + j;                 // 0..5, compile-time
            const int wi = w4 * 9 + r * 3 + j;    // 0..35, compile-time
            const float xv = (e < 4) ? v4[bo][r][e] : v2[bo][r][e - 4];
            s += xv * wq[wi >> 2][wi & 3];
          }
        }
        acc[bo][w4] += s;
      }
    }

    // write next row into the other buffer (per-wave in-order DS => the
    // ds_reads above are already sequenced before these writes; next body's
    // ds_reads of nxt get compiler lgkmcnt ordering)
    if (cc < 3) WSTORE(nxt, n0, n1, nt)
  }
#undef WLOAD
#undef WSTORE

  // ---- stash partials into this wave's buf0 ----
#pragma unroll
  for (int bo = 0; bo < 2; ++bo)
    *(f4*)(buf0 + (2 * q + bo) * 64 + colbase) = acc[bo];
  __syncthreads();  // the only block-wide barrier

  // ---- reduce 4 wave-partials, add bias, coalesced store ----
  for (int p = tid; p < 512; p += 256) {
    const int b  = p >> 6;
    const int wo = p & 63;
    if (wo < WO) {
      float s = smem[0 * 1152 + p] + smem[1 * 1152 + p]
              + smem[2 * 1152 + p] + smem[3 * 1152 + p];
      const int loc = o * NLOC + ho * WO + wo;
      out[(size_t)b * TOTAL + loc] = s + bias[loc];
    }
  }
}

extern "C" void kernel_launch(void* const* d_in, const int* in_sizes, int n_in,
                              void* d_out, int out_size, void* d_ws, size_t ws_size,
                              hipStream_t stream) {
  const float* x = (const float*)d_in[0];
  const float* w = (const float*)d_in[1];
  const float* bias = (const float*)d_in[2];
  float* out = (float*)d_out;

  hipLaunchKernelGGL(lc2d_kernel, dim3(OO * HO), dim3(256), 0, stream,
                     x, w, bias, out);
}

// Round 15
// 25.988 us; speedup vs baseline: 1.1608x; 1.0264x over previous
//
#include <hip/hip_runtime.h>

// LocallyConnected2d: out[b,o,ho,wo] = bias[o,ho,wo]
//   + sum_{c,ki,kj} x[b,c,ho+ki,wo+kj] * w[o,c,ho,wo,ki*3+kj]
//
// Round-15: fully decoupled 2-deep pipeline (the only ordering that breaks
// the in-order-vmcnt coupling shared by r5-r14).
//   Invariant found: draining x(k) force-drains any stage issued BEFORE it.
//   r8/r10 issued stage(cc+1) in body cc, x(cc) in body cc -> stage lead
//   could never exceed ~1 body; every body paid the residual HBM latency.
//   Fix: per body issue x(cc+1) BEFORE stage(cc+2). Then:
//     stage(k): issued body k-2, consumed body k  (2-body lead)
//     x(k):     issued body k-1, consumed body k  (1-body lead)
//   Queue at body-cc entry: [s(cc):3, x(cc):12, s(cc+1):3] = 18.
//   Body cc: issue x(cc+1)[12] -> vmcnt(15) (drains exactly s(cc)+x(cc))
//            -> wq ds_reads -> issue s(cc+2)[3] -> FMA.  Body 3: vmcnt(0).
//   Cost: second x register set (~130 VGPR -> ~12-16 waves/CU). This is the
//   decisive test of the latency-exposure theory; pre-committed branches in
//   the journal.
//  - 3 LDS buffers/wave (stage(k)->buf(k%3)), 27.6 KB/block, no dbuf barriers.
//  - lane (q,l): q=lane>>4 owns b=2q,2q+1; l=lane&15 owns wo=4l..4l+3
//    (f4+f2 window; l=15 dummy f2 flows only into discarded wo 62/63).
//  - epilogue unchanged: per-wave stash, ONE __syncthreads, 4-way reduce.

#define BB 8
#define CC 16
#define HH 64
#define WW 64
#define OO 32
#define HO 62
#define WO 62
#define NLOC (HO * WO)    // 3844
#define TOTAL (OO * NLOC) // 123008

typedef float f4 __attribute__((ext_vector_type(4)));
typedef float f2 __attribute__((ext_vector_type(2)));

__device__ __forceinline__ void async_f32_to_lds(const float* g, float* l) {
  __builtin_amdgcn_global_load_lds((const __attribute__((address_space(1))) void*)g,
                                   (__attribute__((address_space(3))) void*)l,
                                   4, 0, 0);
}
__device__ __forceinline__ void async_f32x4_to_lds(const float* g, float* l) {
  __builtin_amdgcn_global_load_lds((const __attribute__((address_space(1))) void*)g,
                                   (__attribute__((address_space(3))) void*)l,
                                   16, 0, 0);
}

__global__ __launch_bounds__(256) void lc2d_kernel(
    const float* __restrict__ x, const float* __restrict__ weight,
    const float* __restrict__ bias, float* __restrict__ out) {
  // [wave][buf(3)][576]; wave's buf0 region reused for the partial stash
  __shared__ __align__(16) float smem[4 * 3 * 576];  // 27648 B

  const int tid  = threadIdx.x;
  const int lane = tid & 63;
  const int wave = tid >> 6;
  const int l = lane & 15;   // wo-group: wo = 4l..4l+3
  const int q = lane >> 4;   // b-group:  b  = 2q, 2q+1
  const int ho = blockIdx.x % HO;
  const int o  = blockIdx.x / HO;

  float* wbuf = smem + wave * 1728;

  const int colbase = 4 * l;
  const int f2off = (l < 15) ? 4 : -4;  // l=15: dummy in-bounds read, discarded

  const float* wbase = weight + (size_t)(o * CC + wave * 4) * (NLOC * 9)
                              + (size_t)ho * (WO * 9);

  // stage one 558-float weight row: 2x w16 DMA + 1x w4 tail (3 VMEM/wave)
#define STAGE_ROW(SRC, DST)                                            \
  {                                                                    \
    async_f32x4_to_lds((SRC) + lane * 4, (DST));                       \
    async_f32x4_to_lds((SRC) + 256 + lane * 4, (DST) + 256);           \
    if (lane < 46) async_f32_to_lds((SRC) + 512 + lane, (DST) + 512);  \
  }
  // load one body's x into register slot S (12 VMEM/wave)
#define XLOAD(CIDX, S)                                                 \
  {                                                                    \
    _Pragma("unroll")                                                  \
    for (int bo = 0; bo < 2; ++bo) {                                   \
      const float* xb = x + ((size_t)(2 * q + bo) * CC + (CIDX)) * (HH * WW) \
                          + (size_t)ho * WW + colbase;                 \
      _Pragma("unroll")                                                \
      for (int r = 0; r < 3; ++r) {                                    \
        xv4[S][bo][r] = *(const f4*)(xb + r * WW);                     \
        xv2[S][bo][r] = *(const f2*)(xb + r * WW + f2off);             \
      }                                                                \
    }                                                                  \
  }

  f4 xv4[2][2][3];
  f2 xv2[2][2][3];

  // ---- prologue: s(0), x(0), s(1) — x(0) BEFORE s(1), so consuming x(0)
  // leaves s(1) in flight ----
  STAGE_ROW(wbase, wbuf)
  XLOAD(wave * 4, 0)
  STAGE_ROW(wbase + (size_t)1 * (NLOC * 9), wbuf + 576)

  f4 acc[2];
  acc[0] = (f4)0.f;
  acc[1] = (f4)0.f;

#pragma unroll
  for (int cc = 0; cc < 4; ++cc) {
    const int cs = cc & 1;            // compile-time after full unroll
    const int ns = cs ^ 1;
    const float* cur = wbuf + (cc % 3) * 576;

    __builtin_amdgcn_sched_barrier(0);
    // ---- issue x(cc+1) FIRST (younger than s(cc+1): its drain next body
    // will not touch s(cc+2) issued below) ----
    if (cc < 3) XLOAD(wave * 4 + cc + 1, ns)
    __builtin_amdgcn_sched_barrier(0);
    // ---- drain exactly s(cc)+x(cc); s(cc+1)+x(cc+1) stay in flight ----
    if (cc < 3) {
      asm volatile("s_waitcnt vmcnt(15)");
    } else {
      asm volatile("s_waitcnt vmcnt(0)");
    }
    __builtin_amdgcn_sched_barrier(0);

    // ---- weights from LDS: 9x ds_read_b128 ----
    f4 wq[9];
#pragma unroll
    for (int k = 0; k < 9; ++k)
      wq[k] = *(const f4*)(cur + 36 * l + 4 * k);

    __builtin_amdgcn_sched_barrier(0);
    // ---- issue stage(cc+2) (youngest in queue; 2-body lead) ----
    if (cc < 2)
      STAGE_ROW(wbase + (size_t)(cc + 2) * (NLOC * 9), wbuf + ((cc + 2) % 3) * 576)
    __builtin_amdgcn_sched_barrier(0);

    // ---- FMAs on register slot cs ----
#pragma unroll
    for (int bo = 0; bo < 2; ++bo) {
#pragma unroll
      for (int w4 = 0; w4 < 4; ++w4) {
        float s = 0.f;
#pragma unroll
        for (int r = 0; r < 3; ++r) {
#pragma unroll
          for (int j = 0; j < 3; ++j) {
            const int e = w4 + j;                 // 0..5, compile-time
            const int wi = w4 * 9 + r * 3 + j;    // 0..35, compile-time
            const float xv = (e < 4) ? xv4[cs][bo][r][e] : xv2[cs][bo][r][e - 4];
            s += xv * wq[wi >> 2][wi & 3];
          }
        }
        acc[bo][w4] += s;
      }
    }
  }
#undef XLOAD
#undef STAGE_ROW

  // ---- stash partials into this wave's buf0 region (all DMA drained by
  // body-3 vmcnt(0); wq3 reads lgkm-completed before the FMAs that feed acc)
#pragma unroll
  for (int bo = 0; bo < 2; ++bo)
    *(f4*)(wbuf + (2 * q + bo) * 64 + colbase) = acc[bo];
  __syncthreads();  // the only block-wide barrier

  // ---- reduce 4 wave-partials, add bias, coalesced store ----
  for (int p = tid; p < 512; p += 256) {
    const int b  = p >> 6;
    const int wo = p & 63;
    if (wo < WO) {
      float s = smem[0 * 1728 + p] + smem[1 * 1728 + p]
              + smem[2 * 1728 + p] + smem[3 * 1728 + p];
      const int loc = o * NLOC + ho * WO + wo;
      out[(size_t)b * TOTAL + loc] = s + bias[loc];
    }
  }
}

extern "C" void kernel_launch(void* const* d_in, const int* in_sizes, int n_in,
                              void* d_out, int out_size, void* d_ws, size_t ws_size,
                              hipStream_t stream) {
  const float* x = (const float*)d_in[0];
  const float* w = (const float*)d_in[1];
  const float* bias = (const float*)d_in[2];
  float* out = (float*)d_out;

  hipLaunchKernelGGL(lc2d_kernel, dim3(OO * HO), dim3(256), 0, stream,
                     x, w, bias, out);
}